// Round 1
// baseline (1225.514 us; speedup 1.0000x reference)
//
#pragma clang fp contract(off)
#include <hip/hip_runtime.h>
#include <math.h>

#define N_PTS   4096
#define B_SZ    8
#define NPOINT  1024
#define NSAMPLE 32
#define C_FEAT  128
#define C_IN    131
#define C_OUT   256
#define R2      1e-2f   // float(0.1*0.1) as JAX weak-casts it

// ---------------- K0: transpose + channel-reorder W ----------------
// Storage col c: 0..127 -> feature channel (src 3+c), 128..130 -> xyz channel (src c-128)
__global__ void k_wtrans(const float* __restrict__ W, float* __restrict__ Wt) {
    int c = blockIdx.x;          // 0..130
    int o = threadIdx.x;         // 0..255
    int src = (c < C_FEAT) ? (c + 3) : (c - C_FEAT);
    Wt[c * C_OUT + o] = W[o * C_IN + src];
}

// ---------------- K1: furthest point sampling ----------------
#define FPS_BLOCK 512
#define FPS_PPT   8     // points per thread: 512*8 = 4096

__global__ __launch_bounds__(FPS_BLOCK) void k_fps(const float* __restrict__ xyz,
                                                   float* __restrict__ new_xyz) {
    const int b    = blockIdx.x;
    const int t    = threadIdx.x;
    const int lane = t & 63;
    const int wid  = t >> 6;     // 0..7
    __shared__ float xl[N_PTS], yl[N_PTS], zl[N_PTS];
    __shared__ unsigned long long red[2][FPS_BLOCK / 64];

    const float* base = xyz + (size_t)b * N_PTS * 3;
    float px[FPS_PPT], py[FPS_PPT], pz[FPS_PPT], mind[FPS_PPT];

    // load 8 consecutive points = 24 floats = 6 float4 (coalesced)
    const float4* b4 = (const float4*)(base + (size_t)t * (FPS_PPT * 3));
    float4 v[6];
#pragma unroll
    for (int i = 0; i < 6; ++i) v[i] = b4[i];
    const float* vf = (const float*)v;
#pragma unroll
    for (int j = 0; j < FPS_PPT; ++j) {
        px[j] = vf[j * 3 + 0];
        py[j] = vf[j * 3 + 1];
        pz[j] = vf[j * 3 + 2];
        int gi = t * FPS_PPT + j;
        xl[gi] = px[j]; yl[gi] = py[j]; zl[gi] = pz[j];
        mind[j] = 1e10f;
    }
    __syncthreads();

    float cx = xl[0], cy = yl[0], cz = zl[0];
    if (t == 0) {
        float* o = new_xyz + (size_t)b * NPOINT * 3;
        o[0] = cx; o[1] = cy; o[2] = cz;
    }

    for (int it = 1; it < NPOINT; ++it) {
        float bestv = -1.0f;
        int   besti = 0;
#pragma unroll
        for (int j = 0; j < FPS_PPT; ++j) {
            // plain mul/add, contract(off): matches XLA's ((dx^2+dy^2)+dz^2)
            float dx = px[j] - cx;
            float dy = py[j] - cy;
            float dz = pz[j] - cz;
            float d  = ((dx * dx) + (dy * dy)) + (dz * dz);
            float m  = fminf(mind[j], d);
            mind[j]  = m;
            if (m > bestv) { bestv = m; besti = t * FPS_PPT + j; }
        }
        // pack: max over key = max value, ties -> lowest index (first occurrence)
        unsigned long long key = ((unsigned long long)__float_as_uint(bestv) << 32)
                               | (unsigned)(N_PTS - 1 - besti);
#pragma unroll
        for (int off = 1; off < 64; off <<= 1) {
            unsigned long long o = __shfl_xor(key, off);
            key = (o > key) ? o : key;
        }
        if (lane == 0) red[it & 1][wid] = key;
        __syncthreads();
        // every wave redundantly reduces the 8 wave-leader keys (single barrier/iter)
        unsigned long long v2 = red[it & 1][lane & (FPS_BLOCK / 64 - 1)];
#pragma unroll
        for (int off = 1; off < FPS_BLOCK / 64; off <<= 1) {
            unsigned long long o = __shfl_xor(v2, off);
            v2 = (o > v2) ? o : v2;
        }
        int idx = N_PTS - 1 - (int)(v2 & 0xFFFFFFFFull);
        cx = xl[idx]; cy = yl[idx]; cz = zl[idx];
        if (t == 0) {
            float* o = new_xyz + ((size_t)b * NPOINT + it) * 3;
            o[0] = cx; o[1] = cy; o[2] = cz;
        }
    }
}

// ---------------- K2: ball query (first NSAMPLE in index order, pad with first) ----------------
__global__ __launch_bounds__(256) void k_ballquery(const float* __restrict__ xyz,
                                                   const float* __restrict__ new_xyz,
                                                   int* __restrict__ out_idx) {
    const int lane = threadIdx.x & 63;
    const int wid  = threadIdx.x >> 6;
    const int b    = blockIdx.y;
    const int s    = blockIdx.x * 4 + wid;

    const float* xb = xyz + (size_t)b * N_PTS * 3;
    const float* q  = new_xyz + ((size_t)b * NPOINT + s) * 3;
    float qx = q[0], qy = q[1], qz = q[2];
    int* ob = out_idx + ((size_t)b * NPOINT + s) * NSAMPLE;

    int total = 0, first = -1;
    const unsigned long long mlt = (1ull << lane) - 1ull;

    for (int ch = 0; ch < N_PTS / 64; ++ch) {
        int i = ch * 64 + lane;
        float x = xb[i * 3 + 0], y = xb[i * 3 + 1], z = xb[i * 3 + 2];
        float dx = qx - x, dy = qy - y, dz = qz - z;
        float d2 = ((dx * dx) + (dy * dy)) + (dz * dz);
        bool valid = d2 < R2;
        unsigned long long m = __ballot(valid);
        if (valid) {
            int pos = total + __popcll(m & mlt);
            if (pos < NSAMPLE) ob[pos] = i;
        }
        if (first < 0 && m != 0ull) first = ch * 64 + (__ffsll(m) - 1);
        total += __popcll(m);
        if (total >= NSAMPLE) break;
    }
    if (total < NSAMPLE) {
        if (lane >= total && lane < NSAMPLE) ob[lane] = first;
    }
}

// ---------------- K3: gather + BN + ReLU + GEMM + max over samples ----------------
__device__ __forceinline__ float bn_relu(float v, float mean, float scale, float beta) {
    float r = ((v - mean) * scale) + beta;
    return fmaxf(r, 0.0f);
}

__global__ __launch_bounds__(256) void k_group_gemm(
    const float* __restrict__ xyz, const float* __restrict__ feat,
    const float* __restrict__ new_xyz, const int* __restrict__ idx,
    const float* __restrict__ Wt, const float* __restrict__ bias,
    const float* __restrict__ bn_g, const float* __restrict__ bn_b,
    const float* __restrict__ bn_m, const float* __restrict__ bn_v,
    float* __restrict__ out) {
    const int s = blockIdx.x, b = blockIdx.y;
    const int t = threadIdx.x;

    __shared__ float xs[C_IN][36];      // c-major: xs[c][k], k-pad to 36
    __shared__ float sc_l[C_IN], mn_l[C_IN], bt_l[C_IN];
    __shared__ int   idxs[NSAMPLE];
    __shared__ float nq[3];

    if (t < C_IN) {
        float g  = bn_g[t];
        float vv = bn_v[t] + 1e-5f;
        sc_l[t] = g / sqrtf(vv);
        mn_l[t] = bn_m[t];
        bt_l[t] = bn_b[t];
    }
    if (t < NSAMPLE) idxs[t] = idx[((size_t)b * NPOINT + s) * NSAMPLE + t];
    if (t < 3)       nq[t]   = new_xyz[((size_t)b * NPOINT + s) * 3 + t];
    __syncthreads();

    // stage features: 32 rows x 32 float4 = 1024 float4 over 256 threads (4 iters)
    {
        int k = t & 31;
        int qh = t >> 5;               // 0..7
        const float* frow = feat + ((size_t)b * N_PTS + idxs[k]) * C_FEAT;
#pragma unroll
        for (int m = 0; m < 4; ++m) {
            int qq = m * 8 + qh;       // 0..31
            float4 f = *(const float4*)&frow[qq * 4];
            int c0 = qq * 4;           // storage col; input channel = 3 + c0 + j
            xs[c0 + 0][k] = bn_relu(f.x, mn_l[3 + c0 + 0], sc_l[3 + c0 + 0], bt_l[3 + c0 + 0]);
            xs[c0 + 1][k] = bn_relu(f.y, mn_l[3 + c0 + 1], sc_l[3 + c0 + 1], bt_l[3 + c0 + 1]);
            xs[c0 + 2][k] = bn_relu(f.z, mn_l[3 + c0 + 2], sc_l[3 + c0 + 2], bt_l[3 + c0 + 2]);
            xs[c0 + 3][k] = bn_relu(f.w, mn_l[3 + c0 + 3], sc_l[3 + c0 + 3], bt_l[3 + c0 + 3]);
        }
    }
    // stage relative xyz (storage cols 128..130, input channels 0..2)
    if (t < NSAMPLE) {
        int id = idxs[t];
        const float* p = xyz + ((size_t)b * N_PTS + id) * 3;
#pragma unroll
        for (int d = 0; d < 3; ++d) {
            float g = p[d] - nq[d];
            xs[C_FEAT + d][t] = bn_relu(g, mn_l[d], sc_l[d], bt_l[d]);
        }
    }
    __syncthreads();

    // GEMM: 256 threads = 8(tk) x 32(to); thread tile = 4 k x 8 o
    const int tk = t & 7;
    const int to = t >> 3;
    float acc[4][8];
#pragma unroll
    for (int i = 0; i < 4; ++i)
#pragma unroll
        for (int j = 0; j < 8; ++j) acc[i][j] = 0.0f;

    for (int c = 0; c < C_IN; ++c) {
        float4 a  = *(const float4*)&xs[c][tk * 4];
        float4 w0 = *(const float4*)&Wt[(size_t)c * C_OUT + to * 8];
        float4 w1 = *(const float4*)&Wt[(size_t)c * C_OUT + to * 8 + 4];
        float av[4] = {a.x, a.y, a.z, a.w};
        float wv[8] = {w0.x, w0.y, w0.z, w0.w, w1.x, w1.y, w1.z, w1.w};
#pragma unroll
        for (int i = 0; i < 4; ++i)
#pragma unroll
            for (int j = 0; j < 8; ++j)
                acc[i][j] = fmaf(av[i], wv[j], acc[i][j]);
    }

    // max over k: local 4, then butterfly over tk bits (1,2,4)
    float pm[8];
#pragma unroll
    for (int j = 0; j < 8; ++j)
        pm[j] = fmaxf(fmaxf(acc[0][j], acc[1][j]), fmaxf(acc[2][j], acc[3][j]));
#pragma unroll
    for (int off = 1; off < 8; off <<= 1)
#pragma unroll
        for (int j = 0; j < 8; ++j)
            pm[j] = fmaxf(pm[j], __shfl_xor(pm[j], off));

    if (tk == 0) {
#pragma unroll
        for (int j = 0; j < 8; ++j) {
            int o = to * 8 + j;
            out[(size_t)b * C_OUT * NPOINT + (size_t)o * NPOINT + s] = pm[j] + bias[o];
        }
    }
}

extern "C" void kernel_launch(void* const* d_in, const int* in_sizes, int n_in,
                              void* d_out, int out_size, void* d_ws, size_t ws_size,
                              hipStream_t stream) {
    const float* xyz  = (const float*)d_in[0];
    const float* feat = (const float*)d_in[1];
    const float* W    = (const float*)d_in[2];
    const float* bias = (const float*)d_in[3];
    const float* bn_g = (const float*)d_in[4];
    const float* bn_b = (const float*)d_in[5];
    const float* bn_m = (const float*)d_in[6];
    const float* bn_v = (const float*)d_in[7];

    float* new_xyz  = (float*)d_out;                                   // (8,1024,3)
    float* out_feat = (float*)d_out + (size_t)B_SZ * NPOINT * 3;       // (8,256,1024)

    int*   ws_idx = (int*)d_ws;                                        // 1 MB
    float* Wt     = (float*)((char*)d_ws + (size_t)B_SZ * NPOINT * NSAMPLE * sizeof(int));

    hipLaunchKernelGGL(k_wtrans, dim3(C_IN), dim3(C_OUT), 0, stream, W, Wt);
    hipLaunchKernelGGL(k_fps, dim3(B_SZ), dim3(FPS_BLOCK), 0, stream, xyz, new_xyz);
    hipLaunchKernelGGL(k_ballquery, dim3(NPOINT / 4, B_SZ), dim3(256), 0, stream,
                       xyz, new_xyz, ws_idx);
    hipLaunchKernelGGL(k_group_gemm, dim3(NPOINT, B_SZ), dim3(256), 0, stream,
                       xyz, feat, new_xyz, ws_idx, Wt, bias,
                       bn_g, bn_b, bn_m, bn_v, out_feat);
}

// Round 2
// 1025.463 us; speedup vs baseline: 1.1951x; 1.1951x over previous
//
#pragma clang fp contract(off)
#include <hip/hip_runtime.h>
#include <math.h>

#define N_PTS   4096
#define B_SZ    8
#define NPOINT  1024
#define NSAMPLE 32
#define C_FEAT  128
#define C_IN    131
#define C_OUT   256
#define R2      1e-2f   // float(0.1*0.1) as JAX weak-casts it

// ---------------- K0: transpose + channel-reorder W ----------------
// Storage col c: 0..127 -> feature channel (src 3+c), 128..130 -> xyz channel (src c-128)
__global__ void k_wtrans(const float* __restrict__ W, float* __restrict__ Wt) {
    int c = blockIdx.x;          // 0..130
    int o = threadIdx.x;         // 0..255
    int src = (c < C_FEAT) ? (c + 3) : (c - C_FEAT);
    Wt[c * C_OUT + o] = W[o * C_IN + src];
}

// ---------------- K1: furthest point sampling ----------------
#define FPS_BLOCK 512
#define FPS_PPT   8     // points per thread: 512*8 = 4096

// DPP-based wave64 max over int bits (valid: all values are non-negative float
// bits, so signed-int compare == float compare). Result lands in lane 63.
// old = x so masked/invalid lanes are a max no-op.
#define DPP_IMAX(x, ctrl, rmask)                                              \
    do {                                                                      \
        int _y = __builtin_amdgcn_update_dpp(x, x, ctrl, rmask, 0xf, false);  \
        x = (_y > x) ? _y : x;                                                \
    } while (0)

__global__ __launch_bounds__(FPS_BLOCK) void k_fps(const float* __restrict__ xyz,
                                                   float* __restrict__ new_xyz) {
    const int b    = blockIdx.x;
    const int t    = threadIdx.x;
    const int lane = t & 63;
    const int wid  = t >> 6;     // 0..7
    __shared__ float xl[N_PTS], yl[N_PTS], zl[N_PTS];
    __shared__ unsigned long long red[2][FPS_BLOCK / 64];

    const float* base = xyz + (size_t)b * N_PTS * 3;
    float px[FPS_PPT], py[FPS_PPT], pz[FPS_PPT], mind[FPS_PPT];

    // load 8 consecutive points = 24 floats = 6 float4 (coalesced)
    const float4* b4 = (const float4*)(base + (size_t)t * (FPS_PPT * 3));
    float4 v[6];
#pragma unroll
    for (int i = 0; i < 6; ++i) v[i] = b4[i];
    const float* vf = (const float*)v;
#pragma unroll
    for (int j = 0; j < FPS_PPT; ++j) {
        px[j] = vf[j * 3 + 0];
        py[j] = vf[j * 3 + 1];
        pz[j] = vf[j * 3 + 2];
        int gi = t * FPS_PPT + j;
        xl[gi] = px[j]; yl[gi] = py[j]; zl[gi] = pz[j];
        mind[j] = 1e10f;
    }
    __syncthreads();

    float cx = xl[0], cy = yl[0], cz = zl[0];
    if (t == 0) {
        float* o = new_xyz + (size_t)b * NPOINT * 3;
        o[0] = cx; o[1] = cy; o[2] = cz;
    }

    for (int it = 1; it < NPOINT; ++it) {
        float bestv = -1.0f;
        int   besti = 0;
#pragma unroll
        for (int j = 0; j < FPS_PPT; ++j) {
            // plain mul/add, contract(off): matches XLA's ((dx^2+dy^2)+dz^2)
            float dx = px[j] - cx;
            float dy = py[j] - cy;
            float dz = pz[j] - cz;
            float d  = ((dx * dx) + (dy * dy)) + (dz * dz);
            float m  = fminf(mind[j], d);
            mind[j]  = m;
            if (m > bestv) { bestv = m; besti = t * FPS_PPT + j; }  // strict >: lowest j on ties
        }
        // ---- in-wave argmax: DPP max reduce (VALU) + ballot for the lane ----
        const int bb = __float_as_int(bestv);   // >= 0 always (distances >= 0)
        int r = bb;
        DPP_IMAX(r, 0x111, 0xf);   // row_shr:1
        DPP_IMAX(r, 0x112, 0xf);   // row_shr:2
        DPP_IMAX(r, 0x114, 0xf);   // row_shr:4
        DPP_IMAX(r, 0x118, 0xf);   // row_shr:8  -> lane 15 of each row-of-16 has row max
        DPP_IMAX(r, 0x142, 0xa);   // row_bcast:15 -> lanes 31,63 have half maxes
        DPP_IMAX(r, 0x143, 0xc);   // row_bcast:31 -> lane 63 has wave max
        const int vmax = __builtin_amdgcn_readlane(r, 63);          // SGPR broadcast
        const unsigned long long em = __ballot(bb == vmax);         // >=1 bit set
        const int l = __ffsll((unsigned long long)em) - 1;          // lowest lane = lowest index
        const int widx = __builtin_amdgcn_readlane(besti, l);
        if (lane == 0)
            red[it & 1][wid] = ((unsigned long long)(unsigned)vmax << 32)
                             | (unsigned)(N_PTS - 1 - widx);
        __syncthreads();
        // ---- cross-wave: serial VALU scan of 8 keys (strict > keeps lowest wave/index) ----
        unsigned long long best = red[it & 1][0];
#pragma unroll
        for (int w = 1; w < FPS_BLOCK / 64; ++w) {
            unsigned long long o = red[it & 1][w];
            best = (o > best) ? o : best;
        }
        const int idx = N_PTS - 1 - (int)(best & 0xFFFFull);
        cx = xl[idx]; cy = yl[idx]; cz = zl[idx];
        if (t == 0) {
            float* o = new_xyz + ((size_t)b * NPOINT + it) * 3;
            o[0] = cx; o[1] = cy; o[2] = cz;
        }
    }
}

// ---------------- K2: ball query (first NSAMPLE in index order, pad with first) ----------------
__global__ __launch_bounds__(256) void k_ballquery(const float* __restrict__ xyz,
                                                   const float* __restrict__ new_xyz,
                                                   int* __restrict__ out_idx) {
    const int lane = threadIdx.x & 63;
    const int wid  = threadIdx.x >> 6;
    const int b    = blockIdx.y;
    const int s    = blockIdx.x * 4 + wid;

    const float* xb = xyz + (size_t)b * N_PTS * 3;
    const float* q  = new_xyz + ((size_t)b * NPOINT + s) * 3;
    float qx = q[0], qy = q[1], qz = q[2];
    int* ob = out_idx + ((size_t)b * NPOINT + s) * NSAMPLE;

    int total = 0, first = -1;
    const unsigned long long mlt = (1ull << lane) - 1ull;

    for (int ch = 0; ch < N_PTS / 64; ++ch) {
        int i = ch * 64 + lane;
        float x = xb[i * 3 + 0], y = xb[i * 3 + 1], z = xb[i * 3 + 2];
        float dx = qx - x, dy = qy - y, dz = qz - z;
        float d2 = ((dx * dx) + (dy * dy)) + (dz * dz);
        bool valid = d2 < R2;
        unsigned long long m = __ballot(valid);
        if (valid) {
            int pos = total + __popcll(m & mlt);
            if (pos < NSAMPLE) ob[pos] = i;
        }
        if (first < 0 && m != 0ull) first = ch * 64 + (__ffsll(m) - 1);
        total += __popcll(m);
        if (total >= NSAMPLE) break;
    }
    if (total < NSAMPLE) {
        if (lane >= total && lane < NSAMPLE) ob[lane] = first;
    }
}

// ---------------- K3: gather + BN + ReLU + GEMM + max over samples ----------------
__device__ __forceinline__ float bn_relu(float v, float mean, float scale, float beta) {
    float r = ((v - mean) * scale) + beta;
    return fmaxf(r, 0.0f);
}

__global__ __launch_bounds__(256) void k_group_gemm(
    const float* __restrict__ xyz, const float* __restrict__ feat,
    const float* __restrict__ new_xyz, const int* __restrict__ idx,
    const float* __restrict__ Wt, const float* __restrict__ bias,
    const float* __restrict__ bn_g, const float* __restrict__ bn_b,
    const float* __restrict__ bn_m, const float* __restrict__ bn_v,
    float* __restrict__ out) {
    const int s = blockIdx.x, b = blockIdx.y;
    const int t = threadIdx.x;

    __shared__ float xs[C_IN][36];      // c-major: xs[c][k], k-pad to 36
    __shared__ float sc_l[C_IN], mn_l[C_IN], bt_l[C_IN];
    __shared__ int   idxs[NSAMPLE];
    __shared__ float nq[3];

    if (t < C_IN) {
        float g  = bn_g[t];
        float vv = bn_v[t] + 1e-5f;
        sc_l[t] = g / sqrtf(vv);
        mn_l[t] = bn_m[t];
        bt_l[t] = bn_b[t];
    }
    if (t < NSAMPLE) idxs[t] = idx[((size_t)b * NPOINT + s) * NSAMPLE + t];
    if (t < 3)       nq[t]   = new_xyz[((size_t)b * NPOINT + s) * 3 + t];
    __syncthreads();

    // stage features: 32 rows x 32 float4 = 1024 float4 over 256 threads (4 iters)
    {
        int k = t & 31;
        int qh = t >> 5;               // 0..7
        const float* frow = feat + ((size_t)b * N_PTS + idxs[k]) * C_FEAT;
#pragma unroll
        for (int m = 0; m < 4; ++m) {
            int qq = m * 8 + qh;       // 0..31
            float4 f = *(const float4*)&frow[qq * 4];
            int c0 = qq * 4;           // storage col; input channel = 3 + c0 + j
            xs[c0 + 0][k] = bn_relu(f.x, mn_l[3 + c0 + 0], sc_l[3 + c0 + 0], bt_l[3 + c0 + 0]);
            xs[c0 + 1][k] = bn_relu(f.y, mn_l[3 + c0 + 1], sc_l[3 + c0 + 1], bt_l[3 + c0 + 1]);
            xs[c0 + 2][k] = bn_relu(f.z, mn_l[3 + c0 + 2], sc_l[3 + c0 + 2], bt_l[3 + c0 + 2]);
            xs[c0 + 3][k] = bn_relu(f.w, mn_l[3 + c0 + 3], sc_l[3 + c0 + 3], bt_l[3 + c0 + 3]);
        }
    }
    // stage relative xyz (storage cols 128..130, input channels 0..2)
    if (t < NSAMPLE) {
        int id = idxs[t];
        const float* p = xyz + ((size_t)b * N_PTS + id) * 3;
#pragma unroll
        for (int d = 0; d < 3; ++d) {
            float g = p[d] - nq[d];
            xs[C_FEAT + d][t] = bn_relu(g, mn_l[d], sc_l[d], bt_l[d]);
        }
    }
    __syncthreads();

    // GEMM: 256 threads = 8(tk) x 32(to); thread tile = 4 k x 8 o
    const int tk = t & 7;
    const int to = t >> 3;
    float acc[4][8];
#pragma unroll
    for (int i = 0; i < 4; ++i)
#pragma unroll
        for (int j = 0; j < 8; ++j) acc[i][j] = 0.0f;

    for (int c = 0; c < C_IN; ++c) {
        float4 a  = *(const float4*)&xs[c][tk * 4];
        float4 w0 = *(const float4*)&Wt[(size_t)c * C_OUT + to * 8];
        float4 w1 = *(const float4*)&Wt[(size_t)c * C_OUT + to * 8 + 4];
        float av[4] = {a.x, a.y, a.z, a.w};
        float wv[8] = {w0.x, w0.y, w0.z, w0.w, w1.x, w1.y, w1.z, w1.w};
#pragma unroll
        for (int i = 0; i < 4; ++i)
#pragma unroll
            for (int j = 0; j < 8; ++j)
                acc[i][j] = fmaf(av[i], wv[j], acc[i][j]);
    }

    // max over k: local 4, then butterfly over tk bits (1,2,4)
    float pm[8];
#pragma unroll
    for (int j = 0; j < 8; ++j)
        pm[j] = fmaxf(fmaxf(acc[0][j], acc[1][j]), fmaxf(acc[2][j], acc[3][j]));
#pragma unroll
    for (int off = 1; off < 8; off <<= 1)
#pragma unroll
        for (int j = 0; j < 8; ++j)
            pm[j] = fmaxf(pm[j], __shfl_xor(pm[j], off));

    if (tk == 0) {
#pragma unroll
        for (int j = 0; j < 8; ++j) {
            int o = to * 8 + j;
            out[(size_t)b * C_OUT * NPOINT + (size_t)o * NPOINT + s] = pm[j] + bias[o];
        }
    }
}

extern "C" void kernel_launch(void* const* d_in, const int* in_sizes, int n_in,
                              void* d_out, int out_size, void* d_ws, size_t ws_size,
                              hipStream_t stream) {
    const float* xyz  = (const float*)d_in[0];
    const float* feat = (const float*)d_in[1];
    const float* W    = (const float*)d_in[2];
    const float* bias = (const float*)d_in[3];
    const float* bn_g = (const float*)d_in[4];
    const float* bn_b = (const float*)d_in[5];
    const float* bn_m = (const float*)d_in[6];
    const float* bn_v = (const float*)d_in[7];

    float* new_xyz  = (float*)d_out;                                   // (8,1024,3)
    float* out_feat = (float*)d_out + (size_t)B_SZ * NPOINT * 3;       // (8,256,1024)

    int*   ws_idx = (int*)d_ws;                                        // 1 MB
    float* Wt     = (float*)((char*)d_ws + (size_t)B_SZ * NPOINT * NSAMPLE * sizeof(int));

    hipLaunchKernelGGL(k_wtrans, dim3(C_IN), dim3(C_OUT), 0, stream, W, Wt);
    hipLaunchKernelGGL(k_fps, dim3(B_SZ), dim3(FPS_BLOCK), 0, stream, xyz, new_xyz);
    hipLaunchKernelGGL(k_ballquery, dim3(NPOINT / 4, B_SZ), dim3(256), 0, stream,
                       xyz, new_xyz, ws_idx);
    hipLaunchKernelGGL(k_group_gemm, dim3(NPOINT, B_SZ), dim3(256), 0, stream,
                       xyz, feat, new_xyz, ws_idx, Wt, bias,
                       bn_g, bn_b, bn_m, bn_v, out_feat);
}

// Round 3
// 842.791 us; speedup vs baseline: 1.4541x; 1.2167x over previous
//
#pragma clang fp contract(off)
#include <hip/hip_runtime.h>
#include <math.h>

#define N_PTS   4096
#define B_SZ    8
#define NPOINT  1024
#define NSAMPLE 32
#define C_FEAT  128
#define C_IN    131
#define C_OUT   256
#define R2      1e-2f   // float(0.1*0.1) as JAX weak-casts it

#define KT      5       // K tiles of 32 (131 -> 160 padded)
#define NT      16      // N tiles of 16 (256)
#define KPAD    168     // LDS row stride in bf16 elems (168*2B=336B: 16B-aligned, bank-spread)

typedef __attribute__((ext_vector_type(8))) short bf16x8;
typedef __attribute__((ext_vector_type(4))) float f32x4;

__device__ __forceinline__ unsigned short f2bf(float f) {   // RNE, matches hw cvt
    unsigned u = __float_as_uint(f);
    return (unsigned short)((u + 0x7FFF + ((u >> 16) & 1)) >> 16);
}
__device__ __forceinline__ float bf2f(unsigned short h) {
    return __uint_as_float(((unsigned)h) << 16);
}

// ---------------- K0: split W into bf16 hi/lo, pre-swizzled into MFMA B-fragment order ----
// frag element (kt,nt,lane,j) <- W[o=nt*16+(lane&15)][src(k=kt*32+8*(lane>>4)+j)], 0 if k>=131
__global__ __launch_bounds__(64) void k_wtrans(const float* __restrict__ W,
                                               unsigned short* __restrict__ Wb_hi,
                                               unsigned short* __restrict__ Wb_lo) {
    const int blk  = blockIdx.x;            // kt*NT + nt
    const int kt   = blk / NT, nt = blk % NT;
    const int lane = threadIdx.x;
    const int o    = nt * 16 + (lane & 15);
    const int k0   = kt * 32 + (lane >> 4) * 8;
    const size_t base = ((size_t)blk * 64 + lane) * 8;
#pragma unroll
    for (int j = 0; j < 8; ++j) {
        int k = k0 + j;
        float v = 0.0f;
        if (k < C_IN) {
            int src = (k < C_FEAT) ? (k + 3) : (k - C_FEAT);
            v = W[o * C_IN + src];
        }
        unsigned short hh = f2bf(v);
        Wb_hi[base + j] = hh;
        Wb_lo[base + j] = f2bf(v - bf2f(hh));
    }
}

// ---------------- K1: furthest point sampling (unchanged from R2) ----------------
#define FPS_BLOCK 512
#define FPS_PPT   8

#define DPP_IMAX(x, ctrl, rmask)                                              \
    do {                                                                      \
        int _y = __builtin_amdgcn_update_dpp(x, x, ctrl, rmask, 0xf, false);  \
        x = (_y > x) ? _y : x;                                                \
    } while (0)

__global__ __launch_bounds__(FPS_BLOCK) void k_fps(const float* __restrict__ xyz,
                                                   float* __restrict__ new_xyz) {
    const int b    = blockIdx.x;
    const int t    = threadIdx.x;
    const int lane = t & 63;
    const int wid  = t >> 6;
    __shared__ float xl[N_PTS], yl[N_PTS], zl[N_PTS];
    __shared__ unsigned long long red[2][FPS_BLOCK / 64];

    const float* base = xyz + (size_t)b * N_PTS * 3;
    float px[FPS_PPT], py[FPS_PPT], pz[FPS_PPT], mind[FPS_PPT];

    const float4* b4 = (const float4*)(base + (size_t)t * (FPS_PPT * 3));
    float4 v[6];
#pragma unroll
    for (int i = 0; i < 6; ++i) v[i] = b4[i];
    const float* vf = (const float*)v;
#pragma unroll
    for (int j = 0; j < FPS_PPT; ++j) {
        px[j] = vf[j * 3 + 0];
        py[j] = vf[j * 3 + 1];
        pz[j] = vf[j * 3 + 2];
        int gi = t * FPS_PPT + j;
        xl[gi] = px[j]; yl[gi] = py[j]; zl[gi] = pz[j];
        mind[j] = 1e10f;
    }
    __syncthreads();

    float cx = xl[0], cy = yl[0], cz = zl[0];
    if (t == 0) {
        float* o = new_xyz + (size_t)b * NPOINT * 3;
        o[0] = cx; o[1] = cy; o[2] = cz;
    }

    for (int it = 1; it < NPOINT; ++it) {
        float bestv = -1.0f;
        int   besti = 0;
#pragma unroll
        for (int j = 0; j < FPS_PPT; ++j) {
            float dx = px[j] - cx;
            float dy = py[j] - cy;
            float dz = pz[j] - cz;
            float d  = ((dx * dx) + (dy * dy)) + (dz * dz);
            float m  = fminf(mind[j], d);
            mind[j]  = m;
            if (m > bestv) { bestv = m; besti = t * FPS_PPT + j; }
        }
        const int bb = __float_as_int(bestv);
        int r = bb;
        DPP_IMAX(r, 0x111, 0xf);
        DPP_IMAX(r, 0x112, 0xf);
        DPP_IMAX(r, 0x114, 0xf);
        DPP_IMAX(r, 0x118, 0xf);
        DPP_IMAX(r, 0x142, 0xa);
        DPP_IMAX(r, 0x143, 0xc);
        const int vmax = __builtin_amdgcn_readlane(r, 63);
        const unsigned long long em = __ballot(bb == vmax);
        const int l = __ffsll((unsigned long long)em) - 1;
        const int widx = __builtin_amdgcn_readlane(besti, l);
        if (lane == 0)
            red[it & 1][wid] = ((unsigned long long)(unsigned)vmax << 32)
                             | (unsigned)(N_PTS - 1 - widx);
        __syncthreads();
        unsigned long long best = red[it & 1][0];
#pragma unroll
        for (int w = 1; w < FPS_BLOCK / 64; ++w) {
            unsigned long long o = red[it & 1][w];
            best = (o > best) ? o : best;
        }
        const int idx = N_PTS - 1 - (int)(best & 0xFFFFull);
        cx = xl[idx]; cy = yl[idx]; cz = zl[idx];
        if (t == 0) {
            float* o = new_xyz + ((size_t)b * NPOINT + it) * 3;
            o[0] = cx; o[1] = cy; o[2] = cz;
        }
    }
}

// ---------------- K2: ball query (unchanged) ----------------
__global__ __launch_bounds__(256) void k_ballquery(const float* __restrict__ xyz,
                                                   const float* __restrict__ new_xyz,
                                                   int* __restrict__ out_idx) {
    const int lane = threadIdx.x & 63;
    const int wid  = threadIdx.x >> 6;
    const int b    = blockIdx.y;
    const int s    = blockIdx.x * 4 + wid;

    const float* xb = xyz + (size_t)b * N_PTS * 3;
    const float* q  = new_xyz + ((size_t)b * NPOINT + s) * 3;
    float qx = q[0], qy = q[1], qz = q[2];
    int* ob = out_idx + ((size_t)b * NPOINT + s) * NSAMPLE;

    int total = 0, first = -1;
    const unsigned long long mlt = (1ull << lane) - 1ull;

    for (int ch = 0; ch < N_PTS / 64; ++ch) {
        int i = ch * 64 + lane;
        float x = xb[i * 3 + 0], y = xb[i * 3 + 1], z = xb[i * 3 + 2];
        float dx = qx - x, dy = qy - y, dz = qz - z;
        float d2 = ((dx * dx) + (dy * dy)) + (dz * dz);
        bool valid = d2 < R2;
        unsigned long long m = __ballot(valid);
        if (valid) {
            int pos = total + __popcll(m & mlt);
            if (pos < NSAMPLE) ob[pos] = i;
        }
        if (first < 0 && m != 0ull) first = ch * 64 + (__ffsll(m) - 1);
        total += __popcll(m);
        if (total >= NSAMPLE) break;
    }
    if (total < NSAMPLE) {
        if (lane >= total && lane < NSAMPLE) ob[lane] = first;
    }
}

// ---------------- K3: gather + BN + ReLU + split-bf16 MFMA GEMM + max ----------------
__device__ __forceinline__ float bn_relu(float v, float mean, float scale, float beta) {
    float r = ((v - mean) * scale) + beta;
    return fmaxf(r, 0.0f);
}

__global__ __launch_bounds__(256) void k_group_gemm(
    const float* __restrict__ xyz, const float* __restrict__ feat,
    const float* __restrict__ new_xyz, const int* __restrict__ idx,
    const unsigned short* __restrict__ Wb_hi, const unsigned short* __restrict__ Wb_lo,
    const float* __restrict__ bias,
    const float* __restrict__ bn_g, const float* __restrict__ bn_b,
    const float* __restrict__ bn_m, const float* __restrict__ bn_v,
    float* __restrict__ out) {
    const int sx = blockIdx.x;
    const int s  = ((sx & 7) << 7) | (sx >> 3);   // 128-long contiguous s-runs per XCD
    const int b  = blockIdx.y;
    const int t  = threadIdx.x;
    const int lane = t & 63;
    const int w    = t >> 6;                      // wave 0..3 -> ntiles w*4..w*4+3

    __shared__ unsigned short Xh[32][KPAD], Xl[32][KPAD];
    __shared__ float sc_l[C_IN], mn_l[C_IN], bt_l[C_IN];
    __shared__ int   idxs[NSAMPLE];
    __shared__ float nq[3];

    if (t < C_IN) {
        float g  = bn_g[t];
        float vv = bn_v[t] + 1e-5f;
        sc_l[t] = g / sqrtf(vv);
        mn_l[t] = bn_m[t];
        bt_l[t] = bn_b[t];
    }
    if (t < NSAMPLE) idxs[t] = idx[((size_t)b * NPOINT + s) * NSAMPLE + t];
    if (t < 3)       nq[t]   = new_xyz[((size_t)b * NPOINT + s) * 3 + t];
    __syncthreads();

    // stage features -> bf16 hi/lo, layout [row=sample][k] (k storage: 0..127 feat, 128..130 xyz)
    {
        const int ks = t & 31;
        const int qh = t >> 5;                    // 0..7
        const float* frow = feat + ((size_t)b * N_PTS + idxs[ks]) * C_FEAT;
#pragma unroll
        for (int m = 0; m < 4; ++m) {
            int qq = m * 8 + qh;                  // 0..31
            int c0 = qq * 4;
            float4 f = *(const float4*)&frow[c0];
            float v0 = bn_relu(f.x, mn_l[3 + c0 + 0], sc_l[3 + c0 + 0], bt_l[3 + c0 + 0]);
            float v1 = bn_relu(f.y, mn_l[3 + c0 + 1], sc_l[3 + c0 + 1], bt_l[3 + c0 + 1]);
            float v2 = bn_relu(f.z, mn_l[3 + c0 + 2], sc_l[3 + c0 + 2], bt_l[3 + c0 + 2]);
            float v3 = bn_relu(f.w, mn_l[3 + c0 + 3], sc_l[3 + c0 + 3], bt_l[3 + c0 + 3]);
            unsigned short h0 = f2bf(v0), h1 = f2bf(v1), h2 = f2bf(v2), h3 = f2bf(v3);
            uint2 hv, lv;
            hv.x = (unsigned)h0 | ((unsigned)h1 << 16);
            hv.y = (unsigned)h2 | ((unsigned)h3 << 16);
            lv.x = (unsigned)f2bf(v0 - bf2f(h0)) | ((unsigned)f2bf(v1 - bf2f(h1)) << 16);
            lv.y = (unsigned)f2bf(v2 - bf2f(h2)) | ((unsigned)f2bf(v3 - bf2f(h3)) << 16);
            *(uint2*)&Xh[ks][c0] = hv;
            *(uint2*)&Xl[ks][c0] = lv;
        }
    }
    // xyz channels (k=128..130) + zero pad k=131..167
    if (t < 32) {
        const int row = t;
        const int id  = idxs[row];
        const float* p = xyz + ((size_t)b * N_PTS + id) * 3;
        uint4 z4 = {0u, 0u, 0u, 0u};
        uint4 hh = z4, ll = z4;
        unsigned short h[3];
#pragma unroll
        for (int d = 0; d < 3; ++d) {
            float g = p[d] - nq[d];
            float v = bn_relu(g, mn_l[d], sc_l[d], bt_l[d]);
            h[d] = f2bf(v);
            unsigned short lo = f2bf(v - bf2f(h[d]));
            if (d == 0) { hh.x |= h[d];                 ll.x |= lo; }
            if (d == 1) { hh.x |= (unsigned)h[d] << 16; ll.x |= (unsigned)lo << 16; }
            if (d == 2) { hh.y |= h[d];                 ll.y |= lo; }
        }
        *(uint4*)&Xh[row][128] = hh;  *(uint4*)&Xl[row][128] = ll;
        *(uint4*)&Xh[row][136] = z4;  *(uint4*)&Xl[row][136] = z4;
        *(uint4*)&Xh[row][144] = z4;  *(uint4*)&Xl[row][144] = z4;
        *(uint4*)&Xh[row][152] = z4;  *(uint4*)&Xl[row][152] = z4;
        *(uint4*)&Xh[row][160] = z4;  *(uint4*)&Xl[row][160] = z4;
    }
    __syncthreads();

    // MFMA: M=32 (2 mtiles), N per wave = 4 ntiles of 16, K = 5 tiles of 32
    f32x4 zero = {0.f, 0.f, 0.f, 0.f};
    f32x4 acc[2][4];
#pragma unroll
    for (int m = 0; m < 2; ++m)
#pragma unroll
        for (int n = 0; n < 4; ++n) acc[m][n] = zero;

    const int r0 = lane & 15;
#pragma unroll
    for (int kt = 0; kt < KT; ++kt) {
        const int k0 = kt * 32 + (lane >> 4) * 8;
        bf16x8 a0h = *(const bf16x8*)&Xh[r0][k0];
        bf16x8 a1h = *(const bf16x8*)&Xh[16 + r0][k0];
        bf16x8 a0l = *(const bf16x8*)&Xl[r0][k0];
        bf16x8 a1l = *(const bf16x8*)&Xl[16 + r0][k0];
#pragma unroll
        for (int n = 0; n < 4; ++n) {
            const int nt = w * 4 + n;
            const size_t off = (((size_t)kt * NT + nt) * 64 + lane) * 8;
            bf16x8 bh = *(const bf16x8*)&Wb_hi[off];
            bf16x8 bl = *(const bf16x8*)&Wb_lo[off];
            acc[0][n] = __builtin_amdgcn_mfma_f32_16x16x32_bf16(a0h, bh, acc[0][n], 0, 0, 0);
            acc[1][n] = __builtin_amdgcn_mfma_f32_16x16x32_bf16(a1h, bh, acc[1][n], 0, 0, 0);
            acc[0][n] = __builtin_amdgcn_mfma_f32_16x16x32_bf16(a0l, bh, acc[0][n], 0, 0, 0);
            acc[1][n] = __builtin_amdgcn_mfma_f32_16x16x32_bf16(a1l, bh, acc[1][n], 0, 0, 0);
            acc[0][n] = __builtin_amdgcn_mfma_f32_16x16x32_bf16(a0h, bl, acc[0][n], 0, 0, 0);
            acc[1][n] = __builtin_amdgcn_mfma_f32_16x16x32_bf16(a1h, bl, acc[1][n], 0, 0, 0);
        }
    }

    // epilogue: max over all 32 rows (rows live in {reg i} x {lane>>4} x {mtile}) -> col max
#pragma unroll
    for (int n = 0; n < 4; ++n) {
        float m0 = fmaxf(acc[0][n][0], acc[1][n][0]);
        float m1 = fmaxf(acc[0][n][1], acc[1][n][1]);
        float m2 = fmaxf(acc[0][n][2], acc[1][n][2]);
        float m3 = fmaxf(acc[0][n][3], acc[1][n][3]);
        float pm = fmaxf(fmaxf(m0, m1), fmaxf(m2, m3));
        pm = fmaxf(pm, __shfl_xor(pm, 16));
        pm = fmaxf(pm, __shfl_xor(pm, 32));
        if (lane < 16) {
            int o = (w * 4 + n) * 16 + lane;
            out[(size_t)b * C_OUT * NPOINT + (size_t)o * NPOINT + s] = pm + bias[o];
        }
    }
}

extern "C" void kernel_launch(void* const* d_in, const int* in_sizes, int n_in,
                              void* d_out, int out_size, void* d_ws, size_t ws_size,
                              hipStream_t stream) {
    const float* xyz  = (const float*)d_in[0];
    const float* feat = (const float*)d_in[1];
    const float* W    = (const float*)d_in[2];
    const float* bias = (const float*)d_in[3];
    const float* bn_g = (const float*)d_in[4];
    const float* bn_b = (const float*)d_in[5];
    const float* bn_m = (const float*)d_in[6];
    const float* bn_v = (const float*)d_in[7];

    float* new_xyz  = (float*)d_out;                                   // (8,1024,3)
    float* out_feat = (float*)d_out + (size_t)B_SZ * NPOINT * 3;       // (8,256,1024)

    int*            ws_idx = (int*)d_ws;                               // 1 MB
    unsigned short* Wb_hi  = (unsigned short*)((char*)d_ws + (size_t)B_SZ * NPOINT * NSAMPLE * sizeof(int));
    unsigned short* Wb_lo  = Wb_hi + (size_t)KT * NT * 64 * 8;

    hipLaunchKernelGGL(k_wtrans, dim3(KT * NT), dim3(64), 0, stream, W, Wb_hi, Wb_lo);
    hipLaunchKernelGGL(k_fps, dim3(B_SZ), dim3(FPS_BLOCK), 0, stream, xyz, new_xyz);
    hipLaunchKernelGGL(k_ballquery, dim3(NPOINT / 4, B_SZ), dim3(256), 0, stream,
                       xyz, new_xyz, ws_idx);
    hipLaunchKernelGGL(k_group_gemm, dim3(NPOINT, B_SZ), dim3(256), 0, stream,
                       xyz, feat, new_xyz, ws_idx, Wb_hi, Wb_lo, bias,
                       bn_g, bn_b, bn_m, bn_v, out_feat);
}